// Round 14
// baseline (75.784 us; speedup 1.0000x reference)
//
#include <hip/hip_runtime.h>

// n = 8192 points, d = 512, fp32 in, scalar fp32 out.
// Pipeline:
//   (1) fp32 -> fp8 e4m3 convert (+ zero-init packed argmax keys)
//   (2) triangular fused fp8-MFMA GEMM: 256x128 tiles, 8 waves (4x2 of
//       64x64 — per-wave body identical to the proven R13 kernel), BK=64
//       rotation layout, TWO 24KB LDS buffers (48 KB -> 3 blocks/CU),
//       ONE barrier per K-tile, stage-early/wait-late. Dual row/col argmax
//       with butterfly slot-merge via u64 keys (mono(value)<<32 | ~index).
//   (3) per-row ||x - x[I] + 1e-6||_2 -> log   (full fp32)
//   (4) deterministic mean reduce.

#define NPTS 8192
#define DIM  512
#define BM   256
#define BN   128
#define NROWT 32
#define NBLK  1056   // sum_{ti<32}(2ti+2) = 32*33, = 8*132 (XCD-divisible)
#define KT_N 8       // 512 / 64

typedef float f32x4 __attribute__((ext_vector_type(4)));
typedef long  lx2   __attribute__((ext_vector_type(2)));   // 16 B

// f32 -> OCP e4m3fn, round-to-nearest-even; N(0,1) data never clamps.
__device__ __forceinline__ unsigned char f32_to_e4m3(float f) {
  unsigned u = __builtin_bit_cast(unsigned, f);
  unsigned s = (u >> 24) & 0x80u;
  unsigned a = u & 0x7FFFFFFFu;
  float af = __builtin_bit_cast(float, a);
  if (af < 0.015625f) {                    // below min normal 2^-6
    int m = (int)rintf(af * 512.0f);       // RNE; 8 naturally -> 2^-6 normal
    return (unsigned char)(s | (unsigned)m);
  }
  unsigned u2 = a + 0x0007FFFFu + ((a >> 20) & 1u);  // RNE to 3-bit mantissa
  int e = (int)(u2 >> 23) - 127 + 7;
  unsigned m = (u2 >> 20) & 7u;
  if (e > 15) return (unsigned char)(s | 0x7Eu);     // clamp to 448
  return (unsigned char)(s | ((unsigned)e << 3) | m);
}

// Order-preserving f32 -> u32 (branchless).
__device__ __forceinline__ unsigned int mono_f32(float f) {
  unsigned u = __builtin_bit_cast(unsigned, f);
  return u ^ (0x80000000u | (unsigned)((int)u >> 31));
}

__global__ void cvt_fp8_kernel(const float* __restrict__ x,
                               unsigned char* __restrict__ xq,
                               unsigned long long* __restrict__ nn64) {
  int i = blockIdx.x * blockDim.x + threadIdx.x;     // 8 elems per thread
  const float4* xp = reinterpret_cast<const float4*>(x) + 2 * (size_t)i;
  float4 v0 = xp[0], v1 = xp[1];
  unsigned long long w =
      (unsigned long long)f32_to_e4m3(v0.x) |
      ((unsigned long long)f32_to_e4m3(v0.y) << 8) |
      ((unsigned long long)f32_to_e4m3(v0.z) << 16) |
      ((unsigned long long)f32_to_e4m3(v0.w) << 24) |
      ((unsigned long long)f32_to_e4m3(v1.x) << 32) |
      ((unsigned long long)f32_to_e4m3(v1.y) << 40) |
      ((unsigned long long)f32_to_e4m3(v1.z) << 48) |
      ((unsigned long long)f32_to_e4m3(v1.w) << 56);
  reinterpret_cast<unsigned long long*>(xq)[i] = w;
  if (i < NPTS) nn64[i] = 0ull;
}

__device__ __forceinline__ void gload_lds16(const unsigned char* g,
                                            unsigned char* l) {
  __builtin_amdgcn_global_load_lds(
      (__attribute__((address_space(1))) const void*)g,
      (__attribute__((address_space(3))) void*)l, 16, 0, 0);
}

__device__ __forceinline__ unsigned long long kmax(unsigned long long a,
                                                   unsigned long long b) {
  return a > b ? a : b;
}

// Triangular fused fp8 GEMM + dual argmax.
// grid = NBLK, block = 512 (8 waves, 4x2 grid of 64x64 sub-tiles).
// LDS: 2 buffers x (A 16KB + B 8KB) = 48 KB -> 3 blocks/CU.
__global__ __launch_bounds__(512, 4) void tri_gemm_kernel(
    const unsigned char* __restrict__ xq,
    unsigned long long* __restrict__ nn64) {
  __shared__ unsigned char lds[2][24576];

  // Bijective XCD swizzle (1056 = 8*132), then b -> (ti, tj):
  // cum(ti) = ti*(ti+1), tj in [0, 2ti+2). Upper-triangle spill of the
  // last col tile is harmless duplicate coverage.
  const int orig = (int)blockIdx.x;
  int b = (orig & 7) * (NBLK >> 3) + (orig >> 3);
  int ti = (int)((sqrtf(4.0f * (float)b + 1.0f) - 1.0f) * 0.5f);
  while ((ti + 1) * (ti + 2) <= b) ++ti;
  while (ti * (ti + 1) > b) --ti;
  const int tj = b - ti * (ti + 1);

  const int tid  = (int)threadIdx.x;
  const int wid  = tid >> 6;
  const int lane = tid & 63;
  const int wr   = wid >> 1;      // 0..3  (64-row band within 256)
  const int wc   = wid & 1;       // 0..1  (64-col band within 128)
  const int l15  = lane & 15;
  const int l16  = lane >> 4;     // 0..3
  const int arow0 = ti * BM;
  const int bcol0 = tj * BN;

  // Staging: row = 64 B = 4 slots of 16 B. LDS slot s of row r holds global
  // chunk (s - ((r>>1)&3)) & 3  (rotation; proven conflict-free, absmax 0.0).
  // A: 1024 chunks (2/thread), B: 512 chunks (1/thread) -> 3 loads/thread.
#define STAGE(bufi, kt) do {                                                 \
    _Pragma("unroll")                                                        \
    for (int i_ = 0; i_ < 2; ++i_) {                                         \
      const int chunk_ = (i_ << 9) + tid;          /* 0..1023 */             \
      const int row_   = chunk_ >> 2;              /* 0..255 */              \
      const int c_     = ((chunk_ & 3) - ((row_ >> 1) & 3)) & 3;             \
      gload_lds16(xq + (size_t)(arow0 + row_) * DIM + (kt) * 64 + (c_ << 4), \
                  &lds[bufi][chunk_ << 4]);                                   \
    }                                                                        \
    {                                                                        \
      const int chunk_ = tid;                      /* 0..511 */              \
      const int row_   = chunk_ >> 2;              /* 0..127 */              \
      const int c_     = ((chunk_ & 3) - ((row_ >> 1) & 3)) & 3;             \
      gload_lds16(xq + (size_t)(bcol0 + row_) * DIM + (kt) * 64 + (c_ << 4), \
                  &lds[bufi][16384 + (chunk_ << 4)]);                         \
    }                                                                        \
  } while (0)

  // Fragment reads: lane row r = band + l15 reads stored b128 slot
  // (l16 + rot) & 3, rot = (r>>1)&3 = (l15>>1)&3 (bands are x16).
  const int rot = (l15 >> 1) & 3;
  int aoff[4], boff[4];
#pragma unroll
  for (int mi = 0; mi < 4; ++mi)
    aoff[mi] = (wr * 64 + mi * 16 + l15) * 64 + (((l16 + rot) & 3) << 4);
#pragma unroll
  for (int ni = 0; ni < 4; ++ni)
    boff[ni] = 16384 + (wc * 64 + ni * 16 + l15) * 64 + (((l16 + rot) & 3) << 4);

  f32x4 acc[4][4];
#pragma unroll
  for (int mi = 0; mi < 4; ++mi)
#pragma unroll
    for (int ni = 0; ni < 4; ++ni)
      acc[mi][ni] = (f32x4){0.f, 0.f, 0.f, 0.f};

  // Prologue: stage K-tile 0.
  STAGE(0, 0);

  // Stage-early/wait-late (proven R13 schedule, scaled to 8 waves): at
  // barrier u every wave's reads of the OTHER buffer retired, so staging
  // tile u+1 into it right after the barrier is safe.
  for (int u = 0; u < KT_N; ++u) {
    const int cur = u & 1;
    asm volatile("s_waitcnt vmcnt(0)" ::: "memory");    // tile u landed
    asm volatile("s_barrier" ::: "memory");             // buf[cur] published
    if (u + 1 < KT_N) STAGE(cur ^ 1, u + 1);            // prefetch next

    lx2 a2[4], b2[4];
#pragma unroll
    for (int mi = 0; mi < 4; ++mi)
      a2[mi] = *reinterpret_cast<const lx2*>(&lds[cur][aoff[mi]]);
#pragma unroll
    for (int ni = 0; ni < 4; ++ni)
      b2[ni] = *reinterpret_cast<const lx2*>(&lds[cur][boff[ni]]);
    __builtin_amdgcn_s_setprio(1);
#pragma unroll
    for (int mi = 0; mi < 4; ++mi)
#pragma unroll
      for (int ni = 0; ni < 4; ++ni) {
        acc[mi][ni] = __builtin_amdgcn_mfma_f32_16x16x32_fp8_fp8(
            a2[mi][0], b2[ni][0], acc[mi][ni], 0, 0, 0);
        acc[mi][ni] = __builtin_amdgcn_mfma_f32_16x16x32_fp8_fp8(
            a2[mi][1], b2[ni][1], acc[mi][ni], 0, 0, 0);
      }
    __builtin_amdgcn_s_setprio(0);
  }
#undef STAGE

  // ---- Epilogue: dual argmax via butterfly slot-merge (verbatim R13).
  // C/D layout: col(gj)=l15, row(gi)=l16*4+reg. Key = mono(v)<<32 | ~idx.
  // Wave 64x64 sub-tile sits on the global diagonal iff 4ti+wr == 2tj+wc.
  const bool diagw = (4 * ti + wr == 2 * tj + wc);

  // Row side: 16 slots (mi*4+j), each pre-merged over ni.
  unsigned long long K[16];
  const unsigned jb = ~(unsigned)(bcol0 + wc * 64 + l15);
#pragma unroll
  for (int mi = 0; mi < 4; ++mi)
#pragma unroll
    for (int j = 0; j < 4; ++j) {
      unsigned long long best = 0ull;
#pragma unroll
      for (int ni = 0; ni < 4; ++ni) {
        unsigned long long kk =
            ((unsigned long long)mono_f32(acc[mi][ni][j]) << 32) |
            (unsigned)(jb - ni * 16);
        if (diagw && mi == ni && (l16 * 4 + j) == l15) kk = 0ull;
        best = kmax(best, kk);
      }
      K[mi * 4 + j] = best;
    }
  // Butterfly over l15 bits: 15 shuffle-steps.
#pragma unroll
  for (int k = 0; k < 4; ++k) {
    const int m = 1 << k;
    const unsigned kb = (unsigned)(l15 >> k) & 1u;
#pragma unroll
    for (int i = 0; i < (8 >> k); ++i) {
      unsigned long long lo = K[2 * i], hi = K[2 * i + 1];
      unsigned long long keep = kb ? hi : lo;
      unsigned long long send = kb ? lo : hi;
      unsigned long long recv =
          (unsigned long long)__shfl_xor((long long)send, m);
      K[i] = kmax(keep, recv);
    }
  }
  {
    const int gi = arow0 + wr * 64 + (l15 >> 2) * 16 + l16 * 4 + (l15 & 3);
    atomicMax(&nn64[gi], K[0]);
  }

  // Col side: 4 slots (ni), pre-merged over (mi, j); butterfly over l16 bits.
  unsigned long long C[4];
  const unsigned ib = ~(unsigned)(arow0 + wr * 64 + l16 * 4);
#pragma unroll
  for (int ni = 0; ni < 4; ++ni) {
    unsigned long long best = 0ull;
#pragma unroll
    for (int mi = 0; mi < 4; ++mi)
#pragma unroll
      for (int j = 0; j < 4; ++j) {
        unsigned long long kk =
            ((unsigned long long)mono_f32(acc[mi][ni][j]) << 32) |
            (unsigned)(ib - (mi * 16 + j));
        if (diagw && mi == ni && (l16 * 4 + j) == l15) kk = 0ull;
        best = kmax(best, kk);
      }
    C[ni] = best;
  }
#pragma unroll
  for (int k = 0; k < 2; ++k) {
    const int m = 16 << k;
    const unsigned kb = (unsigned)(lane >> (4 + k)) & 1u;
#pragma unroll
    for (int i = 0; i < (2 >> k); ++i) {
      unsigned long long lo = C[2 * i], hi = C[2 * i + 1];
      unsigned long long keep = kb ? hi : lo;
      unsigned long long send = kb ? lo : hi;
      unsigned long long recv =
          (unsigned long long)__shfl_xor((long long)send, m);
      C[i] = kmax(keep, recv);
    }
  }
  {
    const int gj = bcol0 + wc * 64 + l16 * 16 + l15;
    atomicMax(&nn64[gj], C[0]);
  }
}

// rho_r = ||x_r - x_{nn(r)} + 1e-6||_2 ; logs[r] = log(rho + 1e-8).
__global__ void dist_log_kernel(const float* __restrict__ x,
                                const unsigned long long* __restrict__ nn64,
                                float* __restrict__ logs) {
  const int row  = blockIdx.x * 4 + ((int)threadIdx.x >> 6);
  const int lane = (int)threadIdx.x & 63;
  const int nn   = (int)(~(unsigned int)(nn64[row] & 0xFFFFFFFFull)) & (NPTS - 1);
  const float4* xr = reinterpret_cast<const float4*>(x + (size_t)row * DIM);
  const float4* xn = reinterpret_cast<const float4*>(x + (size_t)nn  * DIM);
  float s = 0.f;
#pragma unroll
  for (int i = 0; i < 2; ++i) {
    float4 a = xr[lane + i * 64];
    float4 b = xn[lane + i * 64];
    float d0 = a.x - b.x + 1e-6f;
    float d1 = a.y - b.y + 1e-6f;
    float d2 = a.z - b.z + 1e-6f;
    float d3 = a.w - b.w + 1e-6f;
    s += d0 * d0 + d1 * d1 + d2 * d2 + d3 * d3;
  }
#pragma unroll
  for (int m = 32; m >= 1; m >>= 1) s += __shfl_xor(s, m);
  if (lane == 0) logs[row] = logf(sqrtf(s) + 1e-8f);
}

// Deterministic mean: 1024 threads x 8 sequential adds + LDS tree.
__global__ void final_reduce_kernel(const float* __restrict__ logs,
                                    float* __restrict__ out) {
  __shared__ float sm[1024];
  const int t = (int)threadIdx.x;
  float s = 0.f;
#pragma unroll
  for (int i = 0; i < 8; ++i) s += logs[t * 8 + i];
  sm[t] = s;
  __syncthreads();
  for (int k = 512; k > 0; k >>= 1) {
    if (t < k) sm[t] += sm[t + k];
    __syncthreads();
  }
  if (t == 0) out[0] = -(sm[0] / (float)NPTS);
}

extern "C" void kernel_launch(void* const* d_in, const int* in_sizes, int n_in,
                              void* d_out, int out_size, void* d_ws, size_t ws_size,
                              hipStream_t stream) {
  const float* x = (const float*)d_in[0];
  float* out = (float*)d_out;
  char* ws = (char*)d_ws;

  // Workspace layout (bytes):
  unsigned char*      xq   = (unsigned char*)(ws);                // 4 MB
  unsigned long long* nn64 = (unsigned long long*)(ws + 4194304); // 64 KB
  float*              logs = (float*)(ws + 4259840);              // 32 KB

  cvt_fp8_kernel<<<(NPTS * DIM / 8) / 256, 256, 0, stream>>>(x, xq, nn64);

  tri_gemm_kernel<<<NBLK, 512, 0, stream>>>(xq, nn64);

  dist_log_kernel<<<NPTS / 4, 256, 0, stream>>>(x, nn64, logs);

  final_reduce_kernel<<<1, 1024, 0, stream>>>(logs, out);
}

// Round 15
// 45.830 us; speedup vs baseline: 1.6536x; 1.6536x over previous
//
#include <hip/hip_runtime.h>

// n = 8192 points, d = 512, fp32 in, scalar fp32 out.
// Pipeline:
//   (1) fp32 -> fp8 e4m3 convert (+ zero-init u32 argmax keys)
//   (2) triangular fused MX-fp8 MFMA GEMM (mfma_scale 32x32x64, unit scales;
//       proven R10 loop) with u32-key dual argmax:
//       key = (mono(v) & 0xFFFFE000) | (8191 - idx)  -> atomicMax = argmax
//       with exact first-occurrence ties; value quantized to 19 bits (safe:
//       quant error << top-2 gap).
//   (3) per-row ||x - x[I] + 1e-6||_2 -> log   (full fp32)
//   (4) deterministic mean reduce.

#define NPTS 8192
#define DIM  512
#define BM   128
#define BN   128
#define NTIL 64
#define NBLK (NTIL * (NTIL + 1) / 2)   // 2080 (= 8*260, XCD-divisible)
#define KT_N 8                          // 512 / 64

typedef float f32x16 __attribute__((ext_vector_type(16)));
typedef int   i32x4  __attribute__((ext_vector_type(4)));
typedef int   i32x8  __attribute__((ext_vector_type(8)));

// f32 -> OCP e4m3fn, round-to-nearest-even; N(0,1) data never clamps.
__device__ __forceinline__ unsigned char f32_to_e4m3(float f) {
  unsigned u = __builtin_bit_cast(unsigned, f);
  unsigned s = (u >> 24) & 0x80u;
  unsigned a = u & 0x7FFFFFFFu;
  float af = __builtin_bit_cast(float, a);
  if (af < 0.015625f) {                    // below min normal 2^-6
    int m = (int)rintf(af * 512.0f);       // RNE; 8 naturally -> 2^-6 normal
    return (unsigned char)(s | (unsigned)m);
  }
  unsigned u2 = a + 0x0007FFFFu + ((a >> 20) & 1u);  // RNE to 3-bit mantissa
  int e = (int)(u2 >> 23) - 127 + 7;
  unsigned m = (u2 >> 20) & 7u;
  if (e > 15) return (unsigned char)(s | 0x7Eu);     // clamp to 448
  return (unsigned char)(s | ((unsigned)e << 3) | m);
}

// Order-preserving f32 -> u32 (branchless).
__device__ __forceinline__ unsigned int mono_f32(float f) {
  unsigned u = __builtin_bit_cast(unsigned, f);
  return u ^ (0x80000000u | (unsigned)((int)u >> 31));
}

__global__ void cvt_fp8_kernel(const float* __restrict__ x,
                               unsigned char* __restrict__ xq,
                               unsigned* __restrict__ nn32) {
  int i = blockIdx.x * blockDim.x + threadIdx.x;     // 8 elems per thread
  const float4* xp = reinterpret_cast<const float4*>(x) + 2 * (size_t)i;
  float4 v0 = xp[0], v1 = xp[1];
  unsigned long long w =
      (unsigned long long)f32_to_e4m3(v0.x) |
      ((unsigned long long)f32_to_e4m3(v0.y) << 8) |
      ((unsigned long long)f32_to_e4m3(v0.z) << 16) |
      ((unsigned long long)f32_to_e4m3(v0.w) << 24) |
      ((unsigned long long)f32_to_e4m3(v1.x) << 32) |
      ((unsigned long long)f32_to_e4m3(v1.y) << 40) |
      ((unsigned long long)f32_to_e4m3(v1.z) << 48) |
      ((unsigned long long)f32_to_e4m3(v1.w) << 56);
  reinterpret_cast<unsigned long long*>(xq)[i] = w;
  if (i < NPTS) nn32[i] = 0u;
}

__device__ __forceinline__ void gload_lds16(const unsigned char* g,
                                            unsigned char* l) {
  __builtin_amdgcn_global_load_lds(
      (__attribute__((address_space(1))) const void*)g,
      (__attribute__((address_space(3))) void*)l, 16, 0, 0);
}

__device__ __forceinline__ unsigned umax(unsigned a, unsigned b) {
  return a > b ? a : b;
}

// Triangular fused MX-fp8 GEMM + dual argmax (u32 keys).
// grid = NBLK, block = 256 (4 waves, 2x2 grid of 64x64 sub-tiles; each wave
// = 2x2 of 32x32 MFMA sub-tiles). LDS: 3 x 16 KB -> 3 blocks/CU.
__global__ __launch_bounds__(256, 3) void tri_gemm_kernel(
    const unsigned char* __restrict__ xq,
    unsigned* __restrict__ nn32) {
  __shared__ unsigned char lds[3][16384];

  // XCD-bijective swizzle (2080 = 8*260), then b -> (ti >= tj).
  const int orig = (int)blockIdx.x;
  int b = (orig & 7) * (NBLK >> 3) + (orig >> 3);
  int ti = (int)((sqrtf(8.0f * (float)b + 1.0f) - 1.0f) * 0.5f);
  while ((ti + 1) * (ti + 2) / 2 <= b) ++ti;
  while (ti * (ti + 1) / 2 > b) --ti;
  const int tj = b - ti * (ti + 1) / 2;

  const int tid  = (int)threadIdx.x;
  const int wid  = tid >> 6;
  const int lane = tid & 63;
  const int wr   = wid >> 1;      // 0..1
  const int wc   = wid & 1;       // 0..1
  const int l31  = lane & 31;
  const int h    = lane >> 5;     // 0..1 (k-half within MFMA)
  const int arow0 = ti * BM;
  const int bcol0 = tj * BN;

  // Staging (proven R10): row = 64 B = 4 slots of 16 B. LDS slot s of row r
  // holds global chunk (s - f(r)) & 3, f(r) = ((r>>1)+(r>>3)) & 3.
#define STAGE(bufi, kt) do {                                                 \
    _Pragma("unroll")                                                        \
    for (int i_ = 0; i_ < 2; ++i_) {                                         \
      const int chunk_ = (i_ << 8) + tid;          /* 0..511 */              \
      const int row_   = chunk_ >> 2;              /* 0..127 */              \
      const int f_     = ((row_ >> 1) + (row_ >> 3)) & 3;                    \
      const int c_     = ((chunk_ & 3) - f_) & 3;                            \
      gload_lds16(xq + (size_t)(arow0 + row_) * DIM + (kt) * 64 + (c_ << 4), \
                  &lds[bufi][chunk_ << 4]);                                   \
      gload_lds16(xq + (size_t)(bcol0 + row_) * DIM + (kt) * 64 + (c_ << 4), \
                  &lds[bufi][8192 + (chunk_ << 4)]);                          \
    }                                                                        \
  } while (0)

  // Fragment reads (32x32x64): lane l reads row (l&31), global k-chunks
  // 2h, 2h+1; stored slots (g + f) & 3, f = ((l31>>1)+(l31>>3)) & 3.
  const int fr  = ((l31 >> 1) + (l31 >> 3)) & 3;
  const int s0  = (2 * h + fr) & 3;
  const int s1  = (2 * h + 1 + fr) & 3;
  const int abase = (wr * 64 + l31) * 64;
  const int bbase = 8192 + (wc * 64 + l31) * 64;
  const int aoff0 = abase + (s0 << 4), aoff1 = abase + (s1 << 4);
  const int boff0 = bbase + (s0 << 4), boff1 = bbase + (s1 << 4);

  f32x16 acc[2][2];
#pragma unroll
  for (int mi = 0; mi < 2; ++mi)
#pragma unroll
    for (int ni = 0; ni < 2; ++ni)
#pragma unroll
      for (int r = 0; r < 16; ++r) acc[mi][ni][r] = 0.f;

  // Prologue: 2 K-tiles in flight (depth-2).
  STAGE(0, 0);
  STAGE(1, 1);

  for (int u = 0; u < KT_N; ++u) {
    const int cur = u - (u / 3) * 3;            // u % 3
    if (u == KT_N - 1) {
      asm volatile("s_waitcnt vmcnt(0)" ::: "memory");
    } else {
      asm volatile("s_waitcnt vmcnt(4)" ::: "memory");  // tile u landed
    }
    asm volatile("s_barrier" ::: "memory");             // buf[cur] published
    if (u + 2 < KT_N) {
      const int nb = (u + 2) - ((u + 2) / 3) * 3;
      STAGE(nb, u + 2);                                 // depth-2 prefetch
    }

    i32x8 a8[2], b8[2];
#pragma unroll
    for (int mi = 0; mi < 2; ++mi) {
      i32x4 lo = *reinterpret_cast<const i32x4*>(&lds[cur][aoff0 + mi * 2048]);
      i32x4 hi = *reinterpret_cast<const i32x4*>(&lds[cur][aoff1 + mi * 2048]);
      a8[mi] = (i32x8){lo[0], lo[1], lo[2], lo[3], hi[0], hi[1], hi[2], hi[3]};
    }
#pragma unroll
    for (int ni = 0; ni < 2; ++ni) {
      i32x4 lo = *reinterpret_cast<const i32x4*>(&lds[cur][boff0 + ni * 2048]);
      i32x4 hi = *reinterpret_cast<const i32x4*>(&lds[cur][boff1 + ni * 2048]);
      b8[ni] = (i32x8){lo[0], lo[1], lo[2], lo[3], hi[0], hi[1], hi[2], hi[3]};
    }
    __builtin_amdgcn_s_setprio(1);
#pragma unroll
    for (int mi = 0; mi < 2; ++mi)
#pragma unroll
      for (int ni = 0; ni < 2; ++ni)
        acc[mi][ni] = __builtin_amdgcn_mfma_scale_f32_32x32x64_f8f6f4(
            a8[mi], b8[ni], acc[mi][ni], 0, 0,   // cbsz=fp8, blgp=fp8
            0, 0x7F7F7F7F, 0, 0x7F7F7F7F);       // unit E8M0 scales
    __builtin_amdgcn_s_setprio(0);
  }
#undef STAGE

  // ---- Epilogue: dual argmax, u32 quantized keys.
  // 32x32 C/D layout: col = lane&31, row_local = (reg&3)+8*(reg>>2)+4*h.
  // key = (mono(v) & 0xFFFFE000) | (8191 - idx); max => first-occurrence.
  const bool diagw = (ti == tj) && (wr == wc);

  unsigned M[2][2][16];
#pragma unroll
  for (int mi = 0; mi < 2; ++mi)
#pragma unroll
    for (int ni = 0; ni < 2; ++ni)
#pragma unroll
      for (int r = 0; r < 16; ++r)
        M[mi][ni][r] = mono_f32(acc[mi][ni][r]) & 0xFFFFE000u;

  // Row side: 32 slots (mi*16 + r), pre-merged over ni.
  unsigned K[32];
  const unsigned jb = 8191u - (unsigned)(bcol0 + wc * 64 + l31);
#pragma unroll
  for (int mi = 0; mi < 2; ++mi)
#pragma unroll
    for (int r = 0; r < 16; ++r) {
      const int rl = (r & 3) + 8 * (r >> 2) + 4 * h;
      unsigned best = 0u;
#pragma unroll
      for (int ni = 0; ni < 2; ++ni) {
        unsigned kk = M[mi][ni][r] | (jb - (unsigned)(ni * 32));
        if (diagw && mi == ni && rl == l31) kk = 0u;
        best = umax(best, kk);
      }
      K[mi * 16 + r] = best;
    }
  // Slot-halving butterfly over lane bits 0..4: 31 shuffle-steps (u32).
#pragma unroll
  for (int k = 0; k < 5; ++k) {
    const int m = 1 << k;
    const unsigned kb = (unsigned)(lane >> k) & 1u;
#pragma unroll
    for (int i = 0; i < (16 >> k); ++i) {
      unsigned lo = K[2 * i], hi = K[2 * i + 1];
      unsigned keep = kb ? hi : lo;
      unsigned send = kb ? lo : hi;
      unsigned recv = (unsigned)__shfl_xor((int)send, m);
      K[i] = umax(keep, recv);
    }
  }
  {
    // slot s = l31: mi = s>>4, r = s&15; row uses this lane's h.
    const int s = l31;
    const int gi = arow0 + wr * 64 + (s >> 4) * 32 +
                   ((s & 3) + 8 * ((s & 15) >> 2) + 4 * h);
    atomicMax(&nn32[gi], K[0]);      // 64 lanes -> 64 distinct rows
  }

  // Col side: in-lane merge over (mi, r) per ni, then one xor-32 exchange.
  {
    unsigned C0 = 0u, C1 = 0u;
    const unsigned ib = 8191u - (unsigned)(arow0 + wr * 64);
#pragma unroll
    for (int mi = 0; mi < 2; ++mi)
#pragma unroll
      for (int r = 0; r < 16; ++r) {
        const int rl = (r & 3) + 8 * (r >> 2) + 4 * h;
        const unsigned idxk = ib - (unsigned)(mi * 32 + rl);
        unsigned k0 = M[mi][0][r] | idxk;
        if (diagw && mi == 0 && rl == l31) k0 = 0u;
        C0 = umax(C0, k0);
        unsigned k1 = M[mi][1][r] | idxk;
        if (diagw && mi == 1 && rl == l31) k1 = 0u;
        C1 = umax(C1, k1);
      }
    unsigned keep = h ? C1 : C0;
    unsigned send = h ? C0 : C1;
    unsigned recv = (unsigned)__shfl_xor((int)send, 32);
    unsigned R = umax(keep, recv);
    const int gj = bcol0 + wc * 64 + h * 32 + l31;   // 64 distinct cols
    atomicMax(&nn32[gj], R);
  }
}

// rho_r = ||x_r - x_{nn(r)} + 1e-6||_2 ; logs[r] = log(rho + 1e-8).
__global__ void dist_log_kernel(const float* __restrict__ x,
                                const unsigned* __restrict__ nn32,
                                float* __restrict__ logs) {
  const int row  = blockIdx.x * 4 + ((int)threadIdx.x >> 6);
  const int lane = (int)threadIdx.x & 63;
  const int nn   = 8191 - (int)(nn32[row] & 8191u);
  const float4* xr = reinterpret_cast<const float4*>(x + (size_t)row * DIM);
  const float4* xn = reinterpret_cast<const float4*>(x + (size_t)nn  * DIM);
  float s = 0.f;
#pragma unroll
  for (int i = 0; i < 2; ++i) {
    float4 a = xr[lane + i * 64];
    float4 b = xn[lane + i * 64];
    float d0 = a.x - b.x + 1e-6f;
    float d1 = a.y - b.y + 1e-6f;
    float d2 = a.z - b.z + 1e-6f;
    float d3 = a.w - b.w + 1e-6f;
    s += d0 * d0 + d1 * d1 + d2 * d2 + d3 * d3;
  }
#pragma unroll
  for (int m = 32; m >= 1; m >>= 1) s += __shfl_xor(s, m);
  if (lane == 0) logs[row] = logf(sqrtf(s) + 1e-8f);
}

// Deterministic mean: 1024 threads x 8 sequential adds + LDS tree.
__global__ void final_reduce_kernel(const float* __restrict__ logs,
                                    float* __restrict__ out) {
  __shared__ float sm[1024];
  const int t = (int)threadIdx.x;
  float s = 0.f;
#pragma unroll
  for (int i = 0; i < 8; ++i) s += logs[t * 8 + i];
  sm[t] = s;
  __syncthreads();
  for (int k = 512; k > 0; k >>= 1) {
    if (t < k) sm[t] += sm[t + k];
    __syncthreads();
  }
  if (t == 0) out[0] = -(sm[0] / (float)NPTS);
}

extern "C" void kernel_launch(void* const* d_in, const int* in_sizes, int n_in,
                              void* d_out, int out_size, void* d_ws, size_t ws_size,
                              hipStream_t stream) {
  const float* x = (const float*)d_in[0];
  float* out = (float*)d_out;
  char* ws = (char*)d_ws;

  // Workspace layout (bytes):
  unsigned char* xq   = (unsigned char*)(ws);            // 4 MB
  unsigned*      nn32 = (unsigned*)(ws + 4194304);       // 32 KB
  float*         logs = (float*)(ws + 4227072);          // 32 KB

  cvt_fp8_kernel<<<(NPTS * DIM / 8) / 256, 256, 0, stream>>>(x, xq, nn32);

  tri_gemm_kernel<<<NBLK, 256, 0, stream>>>(xq, nn32);

  dist_log_kernel<<<NPTS / 4, 256, 0, stream>>>(x, nn32, logs);

  final_reduce_kernel<<<1, 1024, 0, stream>>>(logs, out);
}